// Round 1
// baseline (372.442 us; speedup 1.0000x reference)
//
#include <hip/hip_runtime.h>

typedef _Float16 f16;
typedef _Float16 f16x4 __attribute__((ext_vector_type(4)));
typedef _Float16 f16x8 __attribute__((ext_vector_type(8)));
typedef float    f32x4 __attribute__((ext_vector_type(4)));

#define MFMA_F16(a,b,c) __builtin_amdgcn_mfma_f32_16x16x32_f16((a),(b),(c),0,0,0)

static constexpr int B_  = 2;
static constexpr int S_  = 2048;
static constexpr int D_  = 2048;
static constexpr int H_  = 16;
static constexpr int DK_ = 128;
static constexpr int K_  = 2048;   // GEMM inner dim for both GEMMs

__device__ __forceinline__ void gload_lds16(const void* g, void* l) {
  __builtin_amdgcn_global_load_lds(
      (const __attribute__((address_space(1))) void*)g,
      (__attribute__((address_space(3))) void*)l, 16, 0, 0);
}

// ---------------- cast f32 -> f16 ----------------
__global__ __launch_bounds__(256) void cast_f16_kernel(const float* __restrict__ in,
                                                       f16* __restrict__ out, int n4) {
  int i = blockIdx.x * 256 + threadIdx.x;
  int stride = gridDim.x * 256;
  for (int j = i; j < n4; j += stride) {
    float4 v = reinterpret_cast<const float4*>(in)[j];
    f16x4 o = {(f16)v.x, (f16)v.y, (f16)v.z, (f16)v.w};
    reinterpret_cast<f16x4*>(out)[j] = o;
  }
}

// ---------------- GEMM core: C[128x128] = A[128xK] * B[128xK]^T (both row-major, K contig)
__device__ __forceinline__ void gemm_core(const f16* __restrict__ A, const f16* __restrict__ Bw,
                                          int brow, int bcol, f16* As, f16* Bs,
                                          f32x4 (&acc)[4][4]) {
  const int tid = threadIdx.x;
  const int w = tid >> 6, l = tid & 63;
  const int lg = l >> 4, lr = l & 15;
  const int wr = w >> 1, wc = w & 1;
#pragma unroll
  for (int mi = 0; mi < 4; ++mi)
#pragma unroll
    for (int ni = 0; ni < 4; ++ni) acc[mi][ni] = (f32x4){0.f, 0.f, 0.f, 0.f};

  const int rA = brow * 128 + (l >> 2);
  const int rB = bcol * 128 + (l >> 2);
  const int ck = (l & 3) * 8;

  for (int kt = 0; kt < K_ / 32; ++kt) {
    __syncthreads();
#pragma unroll
    for (int i = 0; i < 2; ++i) {
      const int c = w + i * 4;  // 8 chunks of 1KB each
      gload_lds16(A  + (size_t)(rA + c * 16) * K_ + kt * 32 + ck, As + c * 512);
      gload_lds16(Bw + (size_t)(rB + c * 16) * K_ + kt * 32 + ck, Bs + c * 512);
    }
    __syncthreads();
    f16x8 af[4], bf[4];
#pragma unroll
    for (int mi = 0; mi < 4; ++mi)
      af[mi] = *(const f16x8*)(As + (wr * 64 + mi * 16 + lr) * 32 + lg * 8);
#pragma unroll
    for (int ni = 0; ni < 4; ++ni)
      bf[ni] = *(const f16x8*)(Bs + (wc * 64 + ni * 16 + lr) * 32 + lg * 8);
#pragma unroll
    for (int mi = 0; mi < 4; ++mi)
#pragma unroll
      for (int ni = 0; ni < 4; ++ni)
        acc[mi][ni] = MFMA_F16(af[mi], bf[ni], acc[mi][ni]);
  }
}

// ---------------- GEMM 1: qkv = x @ Wqkv^T, epilogue splits into Q(scaled)/K/V [B,H,S,DK] f16
__global__ __launch_bounds__(256) void gemm_qkv_kernel(const f16* __restrict__ xb,
                                                       const f16* __restrict__ wqkv,
                                                       f16* __restrict__ Q,
                                                       f16* __restrict__ Kk,
                                                       f16* __restrict__ V) {
  __shared__ __align__(16) f16 As[4096];
  __shared__ __align__(16) f16 Bs[4096];
  const int bid = blockIdx.x;
  const int swz = (bid & 7) * (1536 / 8) + (bid >> 3);  // 1536 % 8 == 0 -> bijective
  const int brow = swz / 48, bcol = swz % 48;

  f32x4 acc[4][4];
  gemm_core(xb, wqkv, brow, bcol, As, Bs, acc);

  const int tid = threadIdx.x;
  const int w = tid >> 6, l = tid & 63;
  const int lg = l >> 4, lr = l & 15;
  const int wr = w >> 1, wc = w & 1;

  const int which = bcol / 16;         // 0:q 1:k 2:v  (128-col tiles never cross)
  const int h = bcol % 16;             // head, constant per block
  f16* outp = (which == 0) ? Q : ((which == 1) ? Kk : V);
  const float scale = (which == 0) ? 0.08838834764831845f : 1.0f;  // 1/sqrt(128)

#pragma unroll
  for (int mi = 0; mi < 4; ++mi) {
    const int mbase = brow * 128 + wr * 64 + mi * 16 + lg * 4;
#pragma unroll
    for (int ni = 0; ni < 4; ++ni) {
      const int dk = wc * 64 + ni * 16 + lr;
#pragma unroll
      for (int r = 0; r < 4; ++r) {
        const int mm = mbase + r;
        const int b = mm >> 11, s = mm & 2047;
        outp[(((size_t)b * H_ + h) * S_ + s) * DK_ + dk] = (f16)(acc[mi][ni][r] * scale);
      }
    }
  }
}

// ---------------- GEMM 2: out = attn @ Wo^T (fp32 out)
__global__ __launch_bounds__(256) void gemm_out_kernel(const f16* __restrict__ ab,
                                                       const f16* __restrict__ wo,
                                                       float* __restrict__ out) {
  __shared__ __align__(16) f16 As[4096];
  __shared__ __align__(16) f16 Bs[4096];
  const int bid = blockIdx.x;
  const int swz = (bid & 7) * (512 / 8) + (bid >> 3);
  const int brow = swz / 16, bcol = swz % 16;

  f32x4 acc[4][4];
  gemm_core(ab, wo, brow, bcol, As, Bs, acc);

  const int tid = threadIdx.x;
  const int w = tid >> 6, l = tid & 63;
  const int lg = l >> 4, lr = l & 15;
  const int wr = w >> 1, wc = w & 1;

#pragma unroll
  for (int mi = 0; mi < 4; ++mi) {
    const int mbase = brow * 128 + wr * 64 + mi * 16 + lg * 4;
#pragma unroll
    for (int ni = 0; ni < 4; ++ni) {
      const int n = bcol * 128 + wc * 64 + ni * 16 + lr;
#pragma unroll
      for (int r = 0; r < 4; ++r)
        out[(size_t)(mbase + r) * D_ + n] = acc[mi][ni][r];
    }
  }
}

// ---------------- V transpose: V[B,H,S,DK] -> Vt[B,H,DK,S]
__global__ __launch_bounds__(256) void transpose_v_kernel(const f16* __restrict__ V,
                                                          f16* __restrict__ Vt) {
  const int bid = blockIdx.x;           // (((bh)*32 + st)*2 + dt)
  const int dt = bid & 1;
  const int st = (bid >> 1) & 31;
  const int bh = bid >> 6;
  __shared__ __align__(16) f16 t[64][72];
  const int tid = threadIdx.x;
#pragma unroll
  for (int i = 0; i < 2; ++i) {
    const int chunk = i * 256 + tid;
    const int row = chunk >> 3, c8 = chunk & 7;
    f16x8 v = *(const f16x8*)(V + ((size_t)bh * S_ + st * 64 + row) * DK_ + dt * 64 + c8 * 8);
    *(f16x8*)&t[row][c8 * 8] = v;
  }
  __syncthreads();
#pragma unroll
  for (int i = 0; i < 2; ++i) {
    const int chunk = i * 256 + tid;
    const int row = chunk >> 3, c8 = chunk & 7;   // row = dk_local
    f16x8 v;
#pragma unroll
    for (int jj = 0; jj < 8; ++jj) v[jj] = t[c8 * 8 + jj][row];
    *(f16x8*)(Vt + ((size_t)bh * DK_ + dt * 64 + row) * S_ + st * 64 + c8 * 8) = v;
  }
}

// ---------------- flash attention (causal), 4 waves x 16 q-rows, KV tiles of 64
__global__ __launch_bounds__(256) void attn_kernel(const f16* __restrict__ Q,
                                                   const f16* __restrict__ Kg,
                                                   const f16* __restrict__ Vt,
                                                   f16* __restrict__ O) {
  __shared__ __align__(16) unsigned char Ks[64 * 256];    // [64][128] f16, XOR-swizzled
  __shared__ __align__(16) unsigned char Vs[128 * 128];   // [128][64] f16, XOR-swizzled
  __shared__ __align__(16) unsigned char Ps[4][16 * 128]; // per-wave [16][64] f16, swizzled

  const int bid = blockIdx.x;
  const int qt = bid & 31;
  const int h  = (bid >> 5) & 15;
  const int b  = bid >> 9;
  const int bh = b * H_ + h;
  const int tid = threadIdx.x;
  const int w = tid >> 6, l = tid & 63;
  const int lg = l >> 4, lr = l & 15;

  // Q fragments in registers (Q pre-scaled by 1/sqrt(dk))
  const f16* Qg = Q + ((size_t)bh * S_ + qt * 64 + w * 16) * DK_;
  f16x8 qf[4];
#pragma unroll
  for (int kd = 0; kd < 4; ++kd)
    qf[kd] = *(const f16x8*)(Qg + (size_t)lr * DK_ + kd * 32 + lg * 8);

  f32x4 o[8];
#pragma unroll
  for (int n = 0; n < 8; ++n) o[n] = (f32x4){0.f, 0.f, 0.f, 0.f};
  float mrun[4] = {-1e30f, -1e30f, -1e30f, -1e30f};
  float lrun[4] = {0.f, 0.f, 0.f, 0.f};

  const int ntiles = qt + 1;
  for (int kt = 0; kt < ntiles; ++kt) {
    __syncthreads();
    // stage K tile [64][128]
    const f16* Kt = Kg + ((size_t)bh * S_ + kt * 64) * DK_;
#pragma unroll
    for (int i = 0; i < 4; ++i) {
      const int chunk = i * 256 + tid;
      const int row = chunk >> 4, c8 = chunk & 15;
      uint4 v = *(const uint4*)(Kt + (size_t)row * DK_ + c8 * 8);
      *(uint4*)(Ks + row * 256 + ((c8 * 16) ^ ((row & 7) << 4))) = v;
    }
    // stage Vt tile [128][64]
    const f16* Vtt = Vt + (size_t)bh * DK_ * S_ + kt * 64;
#pragma unroll
    for (int i = 0; i < 4; ++i) {
      const int chunk = i * 256 + tid;
      const int row = chunk >> 3, c8 = chunk & 7;
      uint4 v = *(const uint4*)(Vtt + (size_t)row * S_ + c8 * 8);
      *(uint4*)(Vs + row * 128 + ((c8 * 16) ^ ((row & 7) << 4))) = v;
    }
    __syncthreads();

    // S = Q K^T  (per wave: 16 rows x 64 cols)
    f32x4 s[4];
#pragma unroll
    for (int j = 0; j < 4; ++j) s[j] = (f32x4){0.f, 0.f, 0.f, 0.f};
#pragma unroll
    for (int j = 0; j < 4; ++j) {
      const int row = j * 16 + lr;
#pragma unroll
      for (int kd = 0; kd < 4; ++kd) {
        f16x8 kf = *(const f16x8*)(Ks + row * 256 + ((kd * 64 + lg * 16) ^ ((row & 7) << 4)));
        s[j] = MFMA_F16(qf[kd], kf, s[j]);
      }
    }
    // causal mask on the diagonal tile
    if (kt == qt) {
#pragma unroll
      for (int j = 0; j < 4; ++j) {
        const int col = j * 16 + lr;
#pragma unroll
        for (int r = 0; r < 4; ++r) {
          const int qrow = w * 16 + lg * 4 + r;
          if (col > qrow) s[j][r] = -1e30f;
        }
      }
    }
    // row max (rows live in 16-lane groups; reduce over lr)
    float scl[4];
#pragma unroll
    for (int r = 0; r < 4; ++r) {
      float m0 = fmaxf(fmaxf(s[0][r], s[1][r]), fmaxf(s[2][r], s[3][r]));
#pragma unroll
      for (int msk = 1; msk < 16; msk <<= 1) m0 = fmaxf(m0, __shfl_xor(m0, msk, 64));
      const float nm = fmaxf(mrun[r], m0);
      scl[r] = __expf(mrun[r] - nm);
      mrun[r] = nm;
    }
    // P = exp(S - m); row sums; P -> LDS (f16, swizzled)
    float rs[4] = {0.f, 0.f, 0.f, 0.f};
#pragma unroll
    for (int j = 0; j < 4; ++j) {
#pragma unroll
      for (int r = 0; r < 4; ++r) {
        const float p = __expf(fmaxf(s[j][r] - mrun[r], -80.f));
        rs[r] += p;
        const int row = lg * 4 + r;
        const int cb = (j * 16 + lr) * 2;
        *(f16*)(Ps[w] + row * 128 + (cb ^ ((row & 7) << 4))) = (f16)p;
      }
    }
#pragma unroll
    for (int r = 0; r < 4; ++r) {
      float t = rs[r];
#pragma unroll
      for (int msk = 1; msk < 16; msk <<= 1) t += __shfl_xor(t, msk, 64);
      lrun[r] = lrun[r] * scl[r] + t;
    }
#pragma unroll
    for (int n = 0; n < 8; ++n)
#pragma unroll
      for (int r = 0; r < 4; ++r) o[n][r] *= scl[r];

    asm volatile("s_waitcnt lgkmcnt(0)" ::: "memory");  // P writes visible to own wave

    // O += P @ V  (B-fragments from transposed-V LDS: contiguous reads)
#pragma unroll
    for (int ks = 0; ks < 2; ++ks) {
      f16x8 pf = *(const f16x8*)(Ps[w] + lr * 128 + ((ks * 64 + lg * 16) ^ ((lr & 7) << 4)));
#pragma unroll
      for (int n = 0; n < 8; ++n) {
        const int row = n * 16 + lr;
        f16x8 vf = *(const f16x8*)(Vs + row * 128 + ((ks * 64 + lg * 16) ^ ((row & 7) << 4)));
        o[n] = MFMA_F16(pf, vf, o[n]);
      }
    }
  }

  // epilogue: normalize and store [bs, h*128+dk] f16
#pragma unroll
  for (int r = 0; r < 4; ++r) {
    const float inv = 1.0f / lrun[r];
    const int srow = qt * 64 + w * 16 + lg * 4 + r;
    f16* op = O + ((size_t)b * S_ + srow) * D_ + h * DK_;
#pragma unroll
    for (int n = 0; n < 8; ++n) op[n * 16 + lr] = (f16)(o[n][r] * inv);
  }
}

extern "C" void kernel_launch(void* const* d_in, const int* in_sizes, int n_in,
                              void* d_out, int out_size, void* d_ws, size_t ws_size,
                              hipStream_t stream) {
  const float* x    = (const float*)d_in[0];
  const float* wqkv = (const float*)d_in[1];
  const float* wo   = (const float*)d_in[2];
  float* out = (float*)d_out;
  char* ws = (char*)d_ws;

  // workspace layout (bytes); lifetimes allow two reuses
  f16* xb     = (f16*)(ws + 0);          // 16 MB, x in f16   (later reused as attn_o)
  f16* wqkvb  = (f16*)(ws + 16777216);   // 24 MB             (later reused as Vt)
  f16* wob    = (f16*)(ws + 41943040);   // 8 MB
  f16* Qb     = (f16*)(ws + 50331648);   // 16 MB [B,H,S,DK], pre-scaled
  f16* Kb     = (f16*)(ws + 67108864);   // 16 MB [B,H,S,DK]
  f16* Vb     = (f16*)(ws + 83886080);   // 16 MB [B,H,S,DK]
  f16* Vtb    = (f16*)(ws + 16777216);   // reuse wqkvb: [B,H,DK,S]
  f16* attn_o = (f16*)(ws + 0);          // reuse xb: [B*S, D]

  cast_f16_kernel<<<2048, 256, 0, stream>>>(x, xb, 8388608 / 4);
  cast_f16_kernel<<<2048, 256, 0, stream>>>(wqkv, wqkvb, 12582912 / 4);
  cast_f16_kernel<<<1024, 256, 0, stream>>>(wo, wob, 4194304 / 4);

  gemm_qkv_kernel<<<1536, 256, 0, stream>>>(xb, wqkvb, Qb, Kb, Vb);
  transpose_v_kernel<<<2048, 256, 0, stream>>>(Vb, Vtb);
  attn_kernel<<<1024, 256, 0, stream>>>(Qb, Kb, Vtb, attn_o);
  gemm_out_kernel<<<512, 256, 0, stream>>>(attn_o, wob, out);
}

// Round 2
// 305.107 us; speedup vs baseline: 1.2207x; 1.2207x over previous
//
#include <hip/hip_runtime.h>

typedef _Float16 f16;
typedef _Float16 f16x4 __attribute__((ext_vector_type(4)));
typedef _Float16 f16x8 __attribute__((ext_vector_type(8)));
typedef float    f32x4 __attribute__((ext_vector_type(4)));

#define MFMA_F16(a,b,c) __builtin_amdgcn_mfma_f32_16x16x32_f16((a),(b),(c),0,0,0)

static constexpr int B_  = 2;
static constexpr int S_  = 2048;
static constexpr int D_  = 2048;
static constexpr int H_  = 16;
static constexpr int DK_ = 128;
static constexpr int K_  = 2048;   // GEMM inner dim for both GEMMs

__device__ __forceinline__ void gload_lds16(const void* g, void* l) {
  __builtin_amdgcn_global_load_lds(
      (const __attribute__((address_space(1))) void*)g,
      (__attribute__((address_space(3))) void*)l, 16, 0, 0);
}

// ---------------- cast f32 -> f16 ----------------
__global__ __launch_bounds__(256) void cast_f16_kernel(const float* __restrict__ in,
                                                       f16* __restrict__ out, int n4) {
  int i = blockIdx.x * 256 + threadIdx.x;
  int stride = gridDim.x * 256;
  for (int j = i; j < n4; j += stride) {
    float4 v = reinterpret_cast<const float4*>(in)[j];
    f16x4 o = {(f16)v.x, (f16)v.y, (f16)v.z, (f16)v.w};
    reinterpret_cast<f16x4*>(out)[j] = o;
  }
}

// ---------------- GEMM core: C[128x128] = A[128xK] * B[128xK]^T (both row-major, K contig)
__device__ __forceinline__ void gemm_core(const f16* __restrict__ A, const f16* __restrict__ Bw,
                                          int brow, int bcol, f16* As, f16* Bs,
                                          f32x4 (&acc)[4][4]) {
  const int tid = threadIdx.x;
  const int w = tid >> 6, l = tid & 63;
  const int lg = l >> 4, lr = l & 15;
  const int wr = w >> 1, wc = w & 1;
#pragma unroll
  for (int mi = 0; mi < 4; ++mi)
#pragma unroll
    for (int ni = 0; ni < 4; ++ni) acc[mi][ni] = (f32x4){0.f, 0.f, 0.f, 0.f};

  const int rA = brow * 128 + (l >> 2);
  const int rB = bcol * 128 + (l >> 2);
  const int ck = (l & 3) * 8;

  for (int kt = 0; kt < K_ / 32; ++kt) {
    __syncthreads();
#pragma unroll
    for (int i = 0; i < 2; ++i) {
      const int c = w + i * 4;  // 8 chunks of 1KB each
      gload_lds16(A  + (size_t)(rA + c * 16) * K_ + kt * 32 + ck, As + c * 512);
      gload_lds16(Bw + (size_t)(rB + c * 16) * K_ + kt * 32 + ck, Bs + c * 512);
    }
    __syncthreads();
    f16x8 af[4], bf[4];
#pragma unroll
    for (int mi = 0; mi < 4; ++mi)
      af[mi] = *(const f16x8*)(As + (wr * 64 + mi * 16 + lr) * 32 + lg * 8);
#pragma unroll
    for (int ni = 0; ni < 4; ++ni)
      bf[ni] = *(const f16x8*)(Bs + (wc * 64 + ni * 16 + lr) * 32 + lg * 8);
#pragma unroll
    for (int mi = 0; mi < 4; ++mi)
#pragma unroll
      for (int ni = 0; ni < 4; ++ni)
        acc[mi][ni] = MFMA_F16(af[mi], bf[ni], acc[mi][ni]);
  }
}

// ---------------- GEMM 1: qkv = x @ Wqkv^T, epilogue splits into Q(scaled)/K/V [B,H,S,DK] f16
__global__ __launch_bounds__(256) void gemm_qkv_kernel(const f16* __restrict__ xb,
                                                       const f16* __restrict__ wqkv,
                                                       f16* __restrict__ Q,
                                                       f16* __restrict__ Kk,
                                                       f16* __restrict__ V) {
  __shared__ __align__(16) f16 As[4096];
  __shared__ __align__(16) f16 Bs[4096];
  const int bid = blockIdx.x;
  const int swz = (bid & 7) * (1536 / 8) + (bid >> 3);  // 1536 % 8 == 0 -> bijective
  const int brow = swz / 48, bcol = swz % 48;

  f32x4 acc[4][4];
  gemm_core(xb, wqkv, brow, bcol, As, Bs, acc);

  const int tid = threadIdx.x;
  const int w = tid >> 6, l = tid & 63;
  const int lg = l >> 4, lr = l & 15;
  const int wr = w >> 1, wc = w & 1;

  const int which = bcol / 16;         // 0:q 1:k 2:v  (128-col tiles never cross)
  const int h = bcol % 16;             // head, constant per block
  f16* outp = (which == 0) ? Q : ((which == 1) ? Kk : V);
  const float scale = (which == 0) ? 0.08838834764831845f : 1.0f;  // 1/sqrt(128)

#pragma unroll
  for (int mi = 0; mi < 4; ++mi) {
    const int mbase = brow * 128 + wr * 64 + mi * 16 + lg * 4;
#pragma unroll
    for (int ni = 0; ni < 4; ++ni) {
      const int dk = wc * 64 + ni * 16 + lr;
#pragma unroll
      for (int r = 0; r < 4; ++r) {
        const int mm = mbase + r;
        const int b = mm >> 11, s = mm & 2047;
        outp[(((size_t)b * H_ + h) * S_ + s) * DK_ + dk] = (f16)(acc[mi][ni][r] * scale);
      }
    }
  }
}

// ---------------- GEMM 2: out = attn @ Wo^T (fp32 out)
__global__ __launch_bounds__(256) void gemm_out_kernel(const f16* __restrict__ ab,
                                                       const f16* __restrict__ wo,
                                                       float* __restrict__ out) {
  __shared__ __align__(16) f16 As[4096];
  __shared__ __align__(16) f16 Bs[4096];
  const int bid = blockIdx.x;
  const int swz = (bid & 7) * (512 / 8) + (bid >> 3);
  const int brow = swz / 16, bcol = swz % 16;

  f32x4 acc[4][4];
  gemm_core(ab, wo, brow, bcol, As, Bs, acc);

  const int tid = threadIdx.x;
  const int w = tid >> 6, l = tid & 63;
  const int lg = l >> 4, lr = l & 15;
  const int wr = w >> 1, wc = w & 1;

#pragma unroll
  for (int mi = 0; mi < 4; ++mi) {
    const int mbase = brow * 128 + wr * 64 + mi * 16 + lg * 4;
#pragma unroll
    for (int ni = 0; ni < 4; ++ni) {
      const int n = bcol * 128 + wc * 64 + ni * 16 + lr;
#pragma unroll
      for (int r = 0; r < 4; ++r)
        out[(size_t)(mbase + r) * D_ + n] = acc[mi][ni][r];
    }
  }
}

// ---------------- V transpose: V[B,H,S,DK] -> Vt[B,H,DK,S]
__global__ __launch_bounds__(256) void transpose_v_kernel(const f16* __restrict__ V,
                                                          f16* __restrict__ Vt) {
  const int bid = blockIdx.x;           // (((bh)*32 + st)*2 + dt)
  const int dt = bid & 1;
  const int st = (bid >> 1) & 31;
  const int bh = bid >> 6;
  __shared__ __align__(16) f16 t[64][72];
  const int tid = threadIdx.x;
#pragma unroll
  for (int i = 0; i < 2; ++i) {
    const int chunk = i * 256 + tid;
    const int row = chunk >> 3, c8 = chunk & 7;
    f16x8 v = *(const f16x8*)(V + ((size_t)bh * S_ + st * 64 + row) * DK_ + dt * 64 + c8 * 8);
    *(f16x8*)&t[row][c8 * 8] = v;
  }
  __syncthreads();
#pragma unroll
  for (int i = 0; i < 2; ++i) {
    const int chunk = i * 256 + tid;
    const int row = chunk >> 3, c8 = chunk & 7;   // row = dk_local
    f16x8 v;
#pragma unroll
    for (int jj = 0; jj < 8; ++jj) v[jj] = t[c8 * 8 + jj][row];
    *(f16x8*)(Vt + ((size_t)bh * DK_ + dt * 64 + row) * S_ + st * 64 + c8 * 8) = v;
  }
}

// ---------------- flash attention (causal), 4 waves x 16 q-rows, KV tiles of 64
// Load-balanced: each block processes q-tile `pr` then q-tile `31-pr`
// -> every block does exactly 33 k-tile iterations (no triangular drain tail).
__global__ __launch_bounds__(256) void attn_kernel(const f16* __restrict__ Q,
                                                   const f16* __restrict__ Kg,
                                                   const f16* __restrict__ Vt,
                                                   f16* __restrict__ O) {
  __shared__ __align__(16) unsigned char Ks[64 * 256];    // [64][128] f16, XOR-swizzled
  __shared__ __align__(16) unsigned char Vs[128 * 128];   // [128][64] f16, XOR-swizzled
  __shared__ __align__(16) unsigned char Ps[4][16 * 128]; // per-wave [16][64] f16, swizzled

  const int bid = blockIdx.x;
  const int pr = bid & 15;                 // pair index 0..15
  const int h  = (bid >> 4) & 15;
  const int b  = bid >> 8;
  const int bh = b * H_ + h;
  const int tid = threadIdx.x;
  const int w = tid >> 6, l = tid & 63;
  const int lg = l >> 4, lr = l & 15;

  for (int half = 0; half < 2; ++half) {
    const int qt = half ? (31 - pr) : pr;

    // Q fragments in registers (Q pre-scaled by 1/sqrt(dk))
    const f16* Qg = Q + ((size_t)bh * S_ + qt * 64 + w * 16) * DK_;
    f16x8 qf[4];
#pragma unroll
    for (int kd = 0; kd < 4; ++kd)
      qf[kd] = *(const f16x8*)(Qg + (size_t)lr * DK_ + kd * 32 + lg * 8);

    f32x4 o[8];
#pragma unroll
    for (int n = 0; n < 8; ++n) o[n] = (f32x4){0.f, 0.f, 0.f, 0.f};
    float mrun[4] = {-1e30f, -1e30f, -1e30f, -1e30f};
    float lrun[4] = {0.f, 0.f, 0.f, 0.f};

    const int ntiles = qt + 1;
    for (int kt = 0; kt < ntiles; ++kt) {
      __syncthreads();
      // stage K tile [64][128]
      const f16* Kt = Kg + ((size_t)bh * S_ + kt * 64) * DK_;
#pragma unroll
      for (int i = 0; i < 4; ++i) {
        const int chunk = i * 256 + tid;
        const int row = chunk >> 4, c8 = chunk & 15;
        uint4 v = *(const uint4*)(Kt + (size_t)row * DK_ + c8 * 8);
        *(uint4*)(Ks + row * 256 + ((c8 * 16) ^ ((row & 7) << 4))) = v;
      }
      // stage Vt tile [128][64]
      const f16* Vtt = Vt + (size_t)bh * DK_ * S_ + kt * 64;
#pragma unroll
      for (int i = 0; i < 4; ++i) {
        const int chunk = i * 256 + tid;
        const int row = chunk >> 3, c8 = chunk & 7;
        uint4 v = *(const uint4*)(Vtt + (size_t)row * S_ + c8 * 8);
        *(uint4*)(Vs + row * 128 + ((c8 * 16) ^ ((row & 7) << 4))) = v;
      }
      __syncthreads();

      // S = Q K^T  (per wave: 16 rows x 64 cols)
      f32x4 s[4];
#pragma unroll
      for (int j = 0; j < 4; ++j) s[j] = (f32x4){0.f, 0.f, 0.f, 0.f};
#pragma unroll
      for (int j = 0; j < 4; ++j) {
        const int row = j * 16 + lr;
#pragma unroll
        for (int kd = 0; kd < 4; ++kd) {
          f16x8 kf = *(const f16x8*)(Ks + row * 256 + ((kd * 64 + lg * 16) ^ ((row & 7) << 4)));
          s[j] = MFMA_F16(qf[kd], kf, s[j]);
        }
      }
      // causal mask on the diagonal tile
      if (kt == qt) {
#pragma unroll
        for (int j = 0; j < 4; ++j) {
          const int col = j * 16 + lr;
#pragma unroll
          for (int r = 0; r < 4; ++r) {
            const int qrow = w * 16 + lg * 4 + r;
            if (col > qrow) s[j][r] = -1e30f;
          }
        }
      }
      // row max (rows live in 16-lane groups; reduce over lr)
      float scl[4];
#pragma unroll
      for (int r = 0; r < 4; ++r) {
        float m0 = fmaxf(fmaxf(s[0][r], s[1][r]), fmaxf(s[2][r], s[3][r]));
#pragma unroll
        for (int msk = 1; msk < 16; msk <<= 1) m0 = fmaxf(m0, __shfl_xor(m0, msk, 64));
        const float nm = fmaxf(mrun[r], m0);
        scl[r] = __expf(mrun[r] - nm);
        mrun[r] = nm;
      }
      // P = exp(S - m); row sums; P -> LDS (f16, swizzled)
      float rs[4] = {0.f, 0.f, 0.f, 0.f};
#pragma unroll
      for (int j = 0; j < 4; ++j) {
#pragma unroll
        for (int r = 0; r < 4; ++r) {
          const float p = __expf(fmaxf(s[j][r] - mrun[r], -80.f));
          rs[r] += p;
          const int row = lg * 4 + r;
          const int cb = (j * 16 + lr) * 2;
          *(f16*)(Ps[w] + row * 128 + (cb ^ ((row & 7) << 4))) = (f16)p;
        }
      }
#pragma unroll
      for (int r = 0; r < 4; ++r) {
        float t = rs[r];
#pragma unroll
        for (int msk = 1; msk < 16; msk <<= 1) t += __shfl_xor(t, msk, 64);
        lrun[r] = lrun[r] * scl[r] + t;
      }
#pragma unroll
      for (int n = 0; n < 8; ++n)
#pragma unroll
        for (int r = 0; r < 4; ++r) o[n][r] *= scl[r];

      asm volatile("s_waitcnt lgkmcnt(0)" ::: "memory");  // P writes visible to own wave

      // O += P @ V  (B-fragments from transposed-V LDS: contiguous reads)
#pragma unroll
      for (int ks = 0; ks < 2; ++ks) {
        f16x8 pf = *(const f16x8*)(Ps[w] + lr * 128 + ((ks * 64 + lg * 16) ^ ((lr & 7) << 4)));
#pragma unroll
        for (int n = 0; n < 8; ++n) {
          const int row = n * 16 + lr;
          f16x8 vf = *(const f16x8*)(Vs + row * 128 + ((ks * 64 + lg * 16) ^ ((row & 7) << 4)));
          o[n] = MFMA_F16(pf, vf, o[n]);
        }
      }
    }

    // epilogue: normalize and store [bs, h*128+dk] f16
#pragma unroll
    for (int r = 0; r < 4; ++r) {
      const float inv = 1.0f / lrun[r];
      const int srow = qt * 64 + w * 16 + lg * 4 + r;
      f16* op = O + ((size_t)b * S_ + srow) * D_ + h * DK_;
#pragma unroll
      for (int n = 0; n < 8; ++n) op[n * 16 + lr] = (f16)(o[n][r] * inv);
    }
  }
}

extern "C" void kernel_launch(void* const* d_in, const int* in_sizes, int n_in,
                              void* d_out, int out_size, void* d_ws, size_t ws_size,
                              hipStream_t stream) {
  const float* x    = (const float*)d_in[0];
  const float* wqkv = (const float*)d_in[1];
  const float* wo   = (const float*)d_in[2];
  float* out = (float*)d_out;
  char* ws = (char*)d_ws;

  // workspace layout (bytes); lifetimes allow two reuses
  f16* xb     = (f16*)(ws + 0);          // 16 MB, x in f16   (later reused as attn_o)
  f16* wqkvb  = (f16*)(ws + 16777216);   // 24 MB             (later reused as Vt)
  f16* wob    = (f16*)(ws + 41943040);   // 8 MB
  f16* Qb     = (f16*)(ws + 50331648);   // 16 MB [B,H,S,DK], pre-scaled
  f16* Kb     = (f16*)(ws + 67108864);   // 16 MB [B,H,S,DK]
  f16* Vb     = (f16*)(ws + 83886080);   // 16 MB [B,H,S,DK]
  f16* Vtb    = (f16*)(ws + 16777216);   // reuse wqkvb: [B,H,DK,S]
  f16* attn_o = (f16*)(ws + 0);          // reuse xb: [B*S, D]

  cast_f16_kernel<<<2048, 256, 0, stream>>>(x, xb, 8388608 / 4);
  cast_f16_kernel<<<2048, 256, 0, stream>>>(wqkv, wqkvb, 12582912 / 4);
  cast_f16_kernel<<<1024, 256, 0, stream>>>(wo, wob, 4194304 / 4);

  gemm_qkv_kernel<<<1536, 256, 0, stream>>>(xb, wqkvb, Qb, Kb, Vb);
  transpose_v_kernel<<<2048, 256, 0, stream>>>(Vb, Vtb);
  attn_kernel<<<512, 256, 0, stream>>>(Qb, Kb, Vtb, attn_o);
  gemm_out_kernel<<<512, 256, 0, stream>>>(attn_o, wob, out);
}